// Round 1
// baseline (97.572 us; speedup 1.0000x reference)
//
#include <hip/hip_runtime.h>

// SmoothingModule: z_bar[b,t,d] = sum_{k<=t} P_eff[b,k] * prod_{j=k+1..t} q[b,j] * z[b,k,d]
// == linear recurrence s[t] = q[t]*s[t-1] + P_eff[t]*z[t], masked by t < lengths[b].
// Two-pass chunked scan over T. C=64, one block per (b, chunk), one thread per d.

#define CHUNK 64
#define MAX_NC 512  // supports T up to 32768

__global__ __launch_bounds__(512) void k_local(
    const float* __restrict__ z, const float* __restrict__ P,
    float* __restrict__ S, float* __restrict__ A,
    int B, int T, int D, int NC) {
  int blk = blockIdx.x;
  int b = blk / NC, c = blk % NC;
  int t0 = c * CHUNK;
  __shared__ float p_s[CHUNK], q_s[CHUNK];
  int tid = threadIdx.x;
  if (tid < CHUNK) {
    int tg = t0 + tid;
    float p = (tg < T) ? P[(size_t)b * T + tg] : 0.0f;
    p = fminf(fmaxf(p, 0.0f), 1.0f - 1e-6f);
    q_s[tid] = 1.0f - p;
    p_s[tid] = fmaxf(p, 1e-6f);
  }
  __syncthreads();
  int nt = min(CHUNK, T - t0);
  for (int d = tid; d < D; d += blockDim.x) {
    const float* zp = z + ((size_t)b * T + t0) * D + d;
    float s = 0.0f, r = 1.0f;
    for (int t = 0; t < nt; ++t) {
      s = fmaf(q_s[t], s, p_s[t] * zp[(size_t)t * D]);
      r *= q_s[t];
    }
    S[((size_t)b * NC + c) * D + d] = s;
    if (d == 0) A[b * NC + c] = r;  // wave-uniform value, one writer
  }
}

__global__ __launch_bounds__(512) void k_apply(
    const float* __restrict__ z, const float* __restrict__ P,
    const float* __restrict__ S, const float* __restrict__ A,
    const int* __restrict__ lengths, float* __restrict__ out,
    int B, int T, int D, int NC) {
  int blk = blockIdx.x;
  int b = blk / NC, c = blk % NC;
  int t0 = c * CHUNK;
  __shared__ float p_s[CHUNK], q_s[CHUNK];
  __shared__ float a_s[MAX_NC];
  int tid = threadIdx.x;
  if (tid < CHUNK) {
    int tg = t0 + tid;
    float p = (tg < T) ? P[(size_t)b * T + tg] : 0.0f;
    p = fminf(fmaxf(p, 0.0f), 1.0f - 1e-6f);
    q_s[tid] = 1.0f - p;
    p_s[tid] = fmaxf(p, 1e-6f);
  }
  for (int i = tid; i < NC; i += blockDim.x) a_s[i] = A[b * NC + i];
  __syncthreads();
  int L = lengths[b];
  int nt = min(CHUNK, T - t0);
  for (int d = tid; d < D; d += blockDim.x) {
    // carry-in = scan state entering this chunk
    float carry = 0.0f, w = 1.0f;
    for (int cp = c - 1; cp >= 0; --cp) {
      carry = fmaf(S[((size_t)b * NC + cp) * D + d], w, carry);
      w *= a_s[cp];
    }
    const float* zp = z + ((size_t)b * T + t0) * D + d;
    float* op = out + ((size_t)b * T + t0) * D + d;
    float s = carry;
    for (int t = 0; t < nt; ++t) {
      s = fmaf(q_s[t], s, p_s[t] * zp[(size_t)t * D]);
      op[(size_t)t * D] = ((t0 + t) < L) ? s : 0.0f;
    }
  }
}

extern "C" void kernel_launch(void* const* d_in, const int* in_sizes, int n_in,
                              void* d_out, int out_size, void* d_ws, size_t ws_size,
                              hipStream_t stream) {
  const float* z = (const float*)d_in[0];
  const float* P = (const float*)d_in[1];
  const int* lengths = (const int*)d_in[2];
  float* out = (float*)d_out;

  int B = in_sizes[2];
  int T = in_sizes[1] / B;
  int D = in_sizes[0] / in_sizes[1];
  int NC = (T + CHUNK - 1) / CHUNK;

  // workspace: S [B*NC*D] floats, then A [B*NC] floats
  float* S = (float*)d_ws;
  float* A = S + (size_t)B * NC * D;

  dim3 grid(B * NC), block(512);
  k_local<<<grid, block, 0, stream>>>(z, P, S, A, B, T, D, NC);
  k_apply<<<grid, block, 0, stream>>>(z, P, S, A, lengths, out, B, T, D, NC);
}